// Round 4
// baseline (305.103 us; speedup 1.0000x reference)
//
#include <hip/hip_runtime.h>

// SSIM fused, separable 3x3 Gaussian. Block = 320 threads = one full image
// row (2 px/thread), walks a 10-row strip => contiguous 25.6KB slab reads.
// Neighbor pixels via wave shuffle; only lanes 0/63 do masked scalar loads.

#define IMG_H 480
#define IMG_W 640
#define IMG_B 64
#define NPIX (IMG_B * IMG_H * IMG_W)   // 19,660,800
#define ROWS 10
#define STRIPS (IMG_H / ROWS)          // 48
#define NTH 320                        // 5 waves; NTH*2 == IMG_W
#define NBLK (IMG_B * STRIPS)          // 3072
#define FTH 256                        // finalize threads

__device__ __forceinline__ void hfilt2(const float* __restrict__ xr,
                                       const float* __restrict__ yr,
                                       int c, int lane,
                                       float2& mx, float2& my,
                                       float2& sxx, float2& syy, float2& sxy) {
    const float g0 = 0.0113f, g1 = 0.0838f;
    const float2 x2 = *(const float2*)(xr + 2 * c);
    const float2 y2 = *(const float2*)(yr + 2 * c);

    float xl = __shfl_up(x2.y, 1, 64);
    float yl = __shfl_up(y2.y, 1, 64);
    float xg = __shfl_down(x2.x, 1, 64);
    float yg = __shfl_down(y2.x, 1, 64);
    if (lane == 0) {
        xl = (c > 0) ? xr[2 * c - 1] : 0.0f;
        yl = (c > 0) ? yr[2 * c - 1] : 0.0f;
    }
    if (lane == 63) {
        xg = (c < NTH - 1) ? xr[2 * c + 2] : 0.0f;
        yg = (c < NTH - 1) ? yr[2 * c + 2] : 0.0f;
    }

    const float xs0 = xl, xs1 = x2.x, xs2 = x2.y, xs3 = xg;
    const float ys0 = yl, ys1 = y2.x, ys2 = y2.y, ys3 = yg;

    mx.x  = g0 * (xs0 + xs2) + g1 * xs1;
    mx.y  = g0 * (xs1 + xs3) + g1 * xs2;
    my.x  = g0 * (ys0 + ys2) + g1 * ys1;
    my.y  = g0 * (ys1 + ys3) + g1 * ys2;
    sxx.x = g0 * (xs0 * xs0 + xs2 * xs2) + g1 * (xs1 * xs1);
    sxx.y = g0 * (xs1 * xs1 + xs3 * xs3) + g1 * (xs2 * xs2);
    syy.x = g0 * (ys0 * ys0 + ys2 * ys2) + g1 * (ys1 * ys1);
    syy.y = g0 * (ys1 * ys1 + ys3 * ys3) + g1 * (ys2 * ys2);
    sxy.x = g0 * (xs0 * ys0 + xs2 * ys2) + g1 * (xs1 * ys1);
    sxy.y = g0 * (xs1 * ys1 + xs3 * ys3) + g1 * (xs2 * ys2);
}

__device__ __forceinline__ void zero2(float2& a, float2& b, float2& c,
                                      float2& d, float2& e) {
    a = b = c = d = e = make_float2(0.f, 0.f);
}

__global__ __launch_bounds__(NTH, 7) void ssim_partial_kernel(
        const float* __restrict__ x, const float* __restrict__ y,
        float* __restrict__ partials) {
    const float g0 = 0.0113f, g1 = 0.0838f;
    const float C1 = 1e-4f, C2 = 9e-4f;

    const int c    = threadIdx.x;          // 2-px column, 0..319
    const int lane = threadIdx.x & 63;
    const int s    = blockIdx.x % STRIPS;
    const int b    = blockIdx.x / STRIPS;

    const float* xb = x + (size_t)b * IMG_H * IMG_W;
    const float* yb = y + (size_t)b * IMG_H * IMG_W;
    const int h0 = s * ROWS;

    float2 pmx, pmy, psxx, psyy, psxy;
    float2 cmx, cmy, csxx, csyy, csxy;
    float2 nmx, nmy, nsxx, nsyy, nsxy;

    if (h0 > 0) {
        hfilt2(xb + (size_t)(h0 - 1) * IMG_W, yb + (size_t)(h0 - 1) * IMG_W,
               c, lane, pmx, pmy, psxx, psyy, psxy);
    } else {
        zero2(pmx, pmy, psxx, psyy, psxy);
    }
    hfilt2(xb + (size_t)h0 * IMG_W, yb + (size_t)h0 * IMG_W,
           c, lane, cmx, cmy, csxx, csyy, csxy);

    float local = 0.0f;
#pragma unroll 5
    for (int r = 0; r < ROWS; ++r) {
        const int hn = h0 + r + 1;
        if (hn < IMG_H) {
            hfilt2(xb + (size_t)hn * IMG_W, yb + (size_t)hn * IMG_W,
                   c, lane, nmx, nmy, nsxx, nsyy, nsxy);
        } else {
            zero2(nmx, nmy, nsxx, nsyy, nsxy);
        }

        const float vmx0 = g0 * (pmx.x + nmx.x) + g1 * cmx.x;
        const float vmx1 = g0 * (pmx.y + nmx.y) + g1 * cmx.y;
        const float vmy0 = g0 * (pmy.x + nmy.x) + g1 * cmy.x;
        const float vmy1 = g0 * (pmy.y + nmy.y) + g1 * cmy.y;
        const float vxx0 = g0 * (psxx.x + nsxx.x) + g1 * csxx.x;
        const float vxx1 = g0 * (psxx.y + nsxx.y) + g1 * csxx.y;
        const float vyy0 = g0 * (psyy.x + nsyy.x) + g1 * csyy.x;
        const float vyy1 = g0 * (psyy.y + nsyy.y) + g1 * csyy.y;
        const float vxy0 = g0 * (psxy.x + nsxy.x) + g1 * csxy.x;
        const float vxy1 = g0 * (psxy.y + nsxy.y) + g1 * csxy.y;

        {
            const float sx = vxx0 - vmx0 * vmx0;
            const float sy = vyy0 - vmy0 * vmy0;
            const float sxy_ = vxy0 - vmx0 * vmy0;
            const float num = (2.0f * vmx0 * vmy0 + C1) * (2.0f * sxy_ + C2);
            const float den = (vmx0 * vmx0 + vmy0 * vmy0 + C1) * (sx + sy + C2);
            local += num * __builtin_amdgcn_rcpf(den);
        }
        {
            const float sx = vxx1 - vmx1 * vmx1;
            const float sy = vyy1 - vmy1 * vmy1;
            const float sxy_ = vxy1 - vmx1 * vmy1;
            const float num = (2.0f * vmx1 * vmy1 + C1) * (2.0f * sxy_ + C2);
            const float den = (vmx1 * vmx1 + vmy1 * vmy1 + C1) * (sx + sy + C2);
            local += num * __builtin_amdgcn_rcpf(den);
        }

        pmx = cmx; pmy = cmy; psxx = csxx; psyy = csyy; psxy = csxy;
        cmx = nmx; cmy = nmy; csxx = nsxx; csyy = nsyy; csxy = nsxy;
    }

    for (int off = 32; off > 0; off >>= 1)
        local += __shfl_down(local, off, 64);
    __shared__ float sred[NTH / 64];
    const int wid = threadIdx.x >> 6;
    if (lane == 0) sred[wid] = local;
    __syncthreads();
    if (threadIdx.x == 0) {
        float t0 = 0.0f;
#pragma unroll
        for (int i = 0; i < NTH / 64; ++i) t0 += sred[i];
        partials[blockIdx.x] = t0;
    }
}

__global__ void ssim_finalize_kernel(const float* __restrict__ partials,
                                     float* __restrict__ out) {
    double acc = 0.0;
    for (int i = threadIdx.x; i < NBLK; i += FTH)
        acc += (double)partials[i];
    __shared__ double s[FTH];
    s[threadIdx.x] = acc;
    __syncthreads();
    for (int off = FTH / 2; off > 0; off >>= 1) {
        if (threadIdx.x < off) s[threadIdx.x] += s[threadIdx.x + off];
        __syncthreads();
    }
    if (threadIdx.x == 0) {
        const double mean = s[0] / (double)NPIX;
        out[0] = (float)(1.0 - mean);
    }
}

extern "C" void kernel_launch(void* const* d_in, const int* in_sizes, int n_in,
                              void* d_out, int out_size, void* d_ws, size_t ws_size,
                              hipStream_t stream) {
    const float* x = (const float*)d_in[0];
    const float* y = (const float*)d_in[1];
    float* partials = (float*)d_ws;
    float* out = (float*)d_out;

    ssim_partial_kernel<<<NBLK, NTH, 0, stream>>>(x, y, partials);
    ssim_finalize_kernel<<<1, FTH, 0, stream>>>(partials, out);
}

// Round 6
// 187.078 us; speedup vs baseline: 1.6309x; 1.6309x over previous
//
#include <hip/hip_runtime.h>

// SSIM fused, separable 3x3 Gaussian, pending-accumulator vertical filter.
// Thread = 4 px wide, walks ROWS output rows. State = 2 partial-sum rows
// (P1,P2) of 5 maps instead of a 3-row ring. Fully scalarized (no arrays).

#define IMG_H 480
#define IMG_W 640
#define IMG_B 64
#define NPIX (IMG_B * IMG_H * IMG_W)   // 19,660,800
#define ROWS 10
#define STRIPS (IMG_H / ROWS)          // 48
#define QCOLS (IMG_W / 4)              // 160
#define NTH 256
#define NITEMS (IMG_B * STRIPS * QCOLS) // 491,520
#define NBLK (NITEMS / NTH)             // 1920
#define FTH 256

__device__ __forceinline__ float4 f4z() { return make_float4(0.f, 0.f, 0.f, 0.f); }
__device__ __forceinline__ float4 f4s(float s, float4 a) {          // s*a
    return make_float4(s * a.x, s * a.y, s * a.z, s * a.w);
}
__device__ __forceinline__ float4 f4fma(float s, float4 a, float4 b) { // s*a+b
    return make_float4(fmaf(s, a.x, b.x), fmaf(s, a.y, b.y),
                       fmaf(s, a.z, b.z), fmaf(s, a.w, b.w));
}

// Horizontally filter one input row (4 px) into 5 maps.
__device__ __forceinline__ void hfilt4(const float* __restrict__ xp,
                                       const float* __restrict__ yp,
                                       bool has_l, bool has_r,
                                       float4& mx, float4& my,
                                       float4& sxx, float4& syy, float4& sxy) {
    const float g0 = 0.0113f, g1 = 0.0838f;
    const float4 x4 = *(const float4*)xp;
    const float4 y4 = *(const float4*)yp;
    const float xa = has_l ? xp[-1] : 0.0f;
    const float xb = has_r ? xp[4]  : 0.0f;
    const float ya = has_l ? yp[-1] : 0.0f;
    const float yb = has_r ? yp[4]  : 0.0f;

    mx = make_float4(g0 * (xa + x4.y) + g1 * x4.x,
                     g0 * (x4.x + x4.z) + g1 * x4.y,
                     g0 * (x4.y + x4.w) + g1 * x4.z,
                     g0 * (x4.z + xb) + g1 * x4.w);
    my = make_float4(g0 * (ya + y4.y) + g1 * y4.x,
                     g0 * (y4.x + y4.z) + g1 * y4.y,
                     g0 * (y4.y + y4.w) + g1 * y4.z,
                     g0 * (y4.z + yb) + g1 * y4.w);

    const float qxa = xa * xa, qx0 = x4.x * x4.x, qx1 = x4.y * x4.y;
    const float qx2 = x4.z * x4.z, qx3 = x4.w * x4.w, qxb = xb * xb;
    sxx = make_float4(g0 * (qxa + qx1) + g1 * qx0,
                      g0 * (qx0 + qx2) + g1 * qx1,
                      g0 * (qx1 + qx3) + g1 * qx2,
                      g0 * (qx2 + qxb) + g1 * qx3);

    const float qya = ya * ya, qy0 = y4.x * y4.x, qy1 = y4.y * y4.y;
    const float qy2 = y4.z * y4.z, qy3 = y4.w * y4.w, qyb = yb * yb;
    syy = make_float4(g0 * (qya + qy1) + g1 * qy0,
                      g0 * (qy0 + qy2) + g1 * qy1,
                      g0 * (qy1 + qy3) + g1 * qy2,
                      g0 * (qy2 + qyb) + g1 * qy3);

    const float pa = xa * ya, p0 = x4.x * y4.x, p1 = x4.y * y4.y;
    const float p2 = x4.z * y4.z, p3 = x4.w * y4.w, pb = xb * yb;
    sxy = make_float4(g0 * (pa + p1) + g1 * p0,
                      g0 * (p0 + p2) + g1 * p1,
                      g0 * (p1 + p3) + g1 * p2,
                      g0 * (p2 + pb) + g1 * p3);
}

__device__ __forceinline__ float ssim4(float4 mx, float4 my, float4 xx,
                                       float4 yy, float4 xy) {
    const float C1 = 1e-4f, C2 = 9e-4f;
    float acc = 0.0f;
#define SSIM1(MX, MY, XX, YY, XY)                                         \
    {                                                                     \
        const float sx = (XX) - (MX) * (MX);                              \
        const float sy = (YY) - (MY) * (MY);                              \
        const float sxy_ = (XY) - (MX) * (MY);                            \
        const float num = (2.0f * (MX) * (MY) + C1) * (2.0f * sxy_ + C2); \
        const float den = ((MX) * (MX) + (MY) * (MY) + C1) *              \
                          (sx + sy + C2);                                 \
        acc += num * __builtin_amdgcn_rcpf(den);                          \
    }
    SSIM1(mx.x, my.x, xx.x, yy.x, xy.x)
    SSIM1(mx.y, my.y, xx.y, yy.y, xy.y)
    SSIM1(mx.z, my.z, xx.z, yy.z, xy.z)
    SSIM1(mx.w, my.w, xx.w, yy.w, xy.w)
#undef SSIM1
    return acc;
}

__global__ __launch_bounds__(NTH) void ssim_partial_kernel(
        const float* __restrict__ x, const float* __restrict__ y,
        float* __restrict__ partials) {
    const float g0 = 0.0113f, g1 = 0.0838f;

    const int tid = blockIdx.x * NTH + threadIdx.x;
    const int c = tid % QCOLS;
    const int t = tid / QCOLS;
    const int s = t % STRIPS;
    const int b = t / STRIPS;

    const bool has_l = (c > 0);
    const bool has_r = (c < QCOLS - 1);
    const int h0 = s * ROWS;

    const size_t img = (size_t)IMG_H * IMG_W;
    const float* xp = x + (size_t)b * img + (size_t)(h0 - 1) * IMG_W + 4 * c;
    const float* yp = y + (size_t)b * img + (size_t)(h0 - 1) * IMG_W + 4 * c;

    // P1: partial of out[hin-1] (= g0*f(hin-2) + g1*f(hin-1))
    // P2: partial of out[hin]   (= g0*f(hin-1))
    float4 P1mx = f4z(), P1my = f4z(), P1xx = f4z(), P1yy = f4z(), P1xy = f4z();
    float4 P2mx = f4z(), P2my = f4z(), P2xx = f4z(), P2yy = f4z(), P2xy = f4z();

    // it = 0: input row h0-1
    if (h0 > 0) {
        float4 fmx, fmy, fxx, fyy, fxy;
        hfilt4(xp, yp, has_l, has_r, fmx, fmy, fxx, fyy, fxy);
        P2mx = f4s(g0, fmx); P2my = f4s(g0, fmy);
        P2xx = f4s(g0, fxx); P2yy = f4s(g0, fyy); P2xy = f4s(g0, fxy);
    }
    xp += IMG_W; yp += IMG_W;

    float local = 0.0f;
#pragma unroll 2
    for (int it = 1; it <= ROWS + 1; ++it) {
        const int hin = h0 - 1 + it;
        float4 fmx, fmy, fxx, fyy, fxy;
        if (hin < IMG_H) {
            hfilt4(xp, yp, has_l, has_r, fmx, fmy, fxx, fyy, fxy);
        } else {
            fmx = fmy = fxx = fyy = fxy = f4z();
        }

        if (it >= 2) {
            // complete out[hin-1] and fold into the running sum
            const float4 omx = f4fma(g0, fmx, P1mx);
            const float4 omy = f4fma(g0, fmy, P1my);
            const float4 oxx = f4fma(g0, fxx, P1xx);
            const float4 oyy = f4fma(g0, fyy, P1yy);
            const float4 oxy = f4fma(g0, fxy, P1xy);
            local += ssim4(omx, omy, oxx, oyy, oxy);
        }

        // shift partials
        P1mx = f4fma(g1, fmx, P2mx); P1my = f4fma(g1, fmy, P2my);
        P1xx = f4fma(g1, fxx, P2xx); P1yy = f4fma(g1, fyy, P2yy);
        P1xy = f4fma(g1, fxy, P2xy);
        P2mx = f4s(g0, fmx); P2my = f4s(g0, fmy);
        P2xx = f4s(g0, fxx); P2yy = f4s(g0, fyy); P2xy = f4s(g0, fxy);

        xp += IMG_W; yp += IMG_W;
    }

    for (int off = 32; off > 0; off >>= 1)
        local += __shfl_down(local, off, 64);
    __shared__ float sred[NTH / 64];
    const int lane = threadIdx.x & 63;
    const int wid  = threadIdx.x >> 6;
    if (lane == 0) sred[wid] = local;
    __syncthreads();
    if (threadIdx.x == 0) {
        float t0 = 0.0f;
#pragma unroll
        for (int i = 0; i < NTH / 64; ++i) t0 += sred[i];
        partials[blockIdx.x] = t0;
    }
}

__global__ void ssim_finalize_kernel(const float* __restrict__ partials,
                                     float* __restrict__ out) {
    double acc = 0.0;
    for (int i = threadIdx.x; i < NBLK; i += FTH)
        acc += (double)partials[i];
    __shared__ double s[FTH];
    s[threadIdx.x] = acc;
    __syncthreads();
    for (int off = FTH / 2; off > 0; off >>= 1) {
        if (threadIdx.x < off) s[threadIdx.x] += s[threadIdx.x + off];
        __syncthreads();
    }
    if (threadIdx.x == 0) {
        const double mean = s[0] / (double)NPIX;
        out[0] = (float)(1.0 - mean);
    }
}

extern "C" void kernel_launch(void* const* d_in, const int* in_sizes, int n_in,
                              void* d_out, int out_size, void* d_ws, size_t ws_size,
                              hipStream_t stream) {
    const float* x = (const float*)d_in[0];
    const float* y = (const float*)d_in[1];
    float* partials = (float*)d_ws;
    float* out = (float*)d_out;

    ssim_partial_kernel<<<NBLK, NTH, 0, stream>>>(x, y, partials);
    ssim_finalize_kernel<<<1, FTH, 0, stream>>>(partials, out);
}

// Round 7
// 178.484 us; speedup vs baseline: 1.7094x; 1.0482x over previous
//
#include <hip/hip_runtime.h>

// SSIM fused, separable 3x3 Gaussian, pending-accumulator vertical filter,
// software-pipelined: raw loads for row j+1 issue before compute of row j.
// Thread = 4 px wide, walks ROWS output rows. Branchless edge handling.

#define IMG_H 480
#define IMG_W 640
#define IMG_B 64
#define NPIX (IMG_B * IMG_H * IMG_W)   // 19,660,800
#define ROWS 15
#define STRIPS (IMG_H / ROWS)          // 32
#define QCOLS (IMG_W / 4)              // 160
#define NTH 256
#define NITEMS (IMG_B * STRIPS * QCOLS) // 327,680
#define NBLK (NITEMS / NTH)             // 1280 = 5 blocks/CU exactly
#define FTH 256

struct Raw { float4 x4, y4; float xa, xb, ya, yb; };

__device__ __forceinline__ float4 f4z() { return make_float4(0.f, 0.f, 0.f, 0.f); }
__device__ __forceinline__ float4 f4s(float s, float4 a) {
    return make_float4(s * a.x, s * a.y, s * a.z, s * a.w);
}
__device__ __forceinline__ float4 f4fma(float s, float4 a, float4 b) {
    return make_float4(fmaf(s, a.x, b.x), fmaf(s, a.y, b.y),
                       fmaf(s, a.z, b.z), fmaf(s, a.w, b.w));
}

// Unconditional clamped loads — always in-bounds, maskable later.
__device__ __forceinline__ void load_raw(const float* __restrict__ xp,
                                         const float* __restrict__ yp,
                                         int off_l, int off_r, Raw& r) {
    r.x4 = *(const float4*)xp;
    r.y4 = *(const float4*)yp;
    r.xa = xp[off_l];
    r.xb = xp[off_r];
    r.ya = yp[off_l];
    r.yb = yp[off_r];
}

// Horizontal filter of one raw row into 5 maps, with validity masks.
__device__ __forceinline__ void hfilt4m(const Raw& r, bool v, bool has_l, bool has_r,
                                        float4& mx, float4& my,
                                        float4& sxx, float4& syy, float4& sxy) {
    const float g0 = 0.0113f, g1 = 0.0838f;
    const float x0 = v ? r.x4.x : 0.f, x1 = v ? r.x4.y : 0.f;
    const float x2 = v ? r.x4.z : 0.f, x3 = v ? r.x4.w : 0.f;
    const float y0 = v ? r.y4.x : 0.f, y1 = v ? r.y4.y : 0.f;
    const float y2 = v ? r.y4.z : 0.f, y3 = v ? r.y4.w : 0.f;
    const float xa = (v && has_l) ? r.xa : 0.f;
    const float xb = (v && has_r) ? r.xb : 0.f;
    const float ya = (v && has_l) ? r.ya : 0.f;
    const float yb = (v && has_r) ? r.yb : 0.f;

    mx = make_float4(g0 * (xa + x1) + g1 * x0,
                     g0 * (x0 + x2) + g1 * x1,
                     g0 * (x1 + x3) + g1 * x2,
                     g0 * (x2 + xb) + g1 * x3);
    my = make_float4(g0 * (ya + y1) + g1 * y0,
                     g0 * (y0 + y2) + g1 * y1,
                     g0 * (y1 + y3) + g1 * y2,
                     g0 * (y2 + yb) + g1 * y3);

    const float qxa = xa * xa, qx0 = x0 * x0, qx1 = x1 * x1;
    const float qx2 = x2 * x2, qx3 = x3 * x3, qxb = xb * xb;
    sxx = make_float4(g0 * (qxa + qx1) + g1 * qx0,
                      g0 * (qx0 + qx2) + g1 * qx1,
                      g0 * (qx1 + qx3) + g1 * qx2,
                      g0 * (qx2 + qxb) + g1 * qx3);

    const float qya = ya * ya, qy0 = y0 * y0, qy1 = y1 * y1;
    const float qy2 = y2 * y2, qy3 = y3 * y3, qyb = yb * yb;
    syy = make_float4(g0 * (qya + qy1) + g1 * qy0,
                      g0 * (qy0 + qy2) + g1 * qy1,
                      g0 * (qy1 + qy3) + g1 * qy2,
                      g0 * (qy2 + qyb) + g1 * qy3);

    const float pa = xa * ya, p0 = x0 * y0, p1 = x1 * y1;
    const float p2 = x2 * y2, p3 = x3 * y3, pb = xb * yb;
    sxy = make_float4(g0 * (pa + p1) + g1 * p0,
                      g0 * (p0 + p2) + g1 * p1,
                      g0 * (p1 + p3) + g1 * p2,
                      g0 * (p2 + pb) + g1 * p3);
}

__device__ __forceinline__ float ssim4(float4 mx, float4 my, float4 xx,
                                       float4 yy, float4 xy) {
    const float C1 = 1e-4f, C2 = 9e-4f;
    float acc = 0.0f;
#define SSIM1(MX, MY, XX, YY, XY)                                         \
    {                                                                     \
        const float sx = (XX) - (MX) * (MX);                              \
        const float sy = (YY) - (MY) * (MY);                              \
        const float sxy_ = (XY) - (MX) * (MY);                            \
        const float num = (2.0f * (MX) * (MY) + C1) * (2.0f * sxy_ + C2); \
        const float den = ((MX) * (MX) + (MY) * (MY) + C1) *              \
                          (sx + sy + C2);                                 \
        acc += num * __builtin_amdgcn_rcpf(den);                          \
    }
    SSIM1(mx.x, my.x, xx.x, yy.x, xy.x)
    SSIM1(mx.y, my.y, xx.y, yy.y, xy.y)
    SSIM1(mx.z, my.z, xx.z, yy.z, xy.z)
    SSIM1(mx.w, my.w, xx.w, yy.w, xy.w)
#undef SSIM1
    return acc;
}

__global__ __launch_bounds__(NTH) void ssim_partial_kernel(
        const float* __restrict__ x, const float* __restrict__ y,
        float* __restrict__ partials) {
    const float g0 = 0.0113f, g1 = 0.0838f;

    const int tid = blockIdx.x * NTH + threadIdx.x;
    const int c = tid % QCOLS;
    const int t = tid / QCOLS;
    const int s = t % STRIPS;
    const int b = t / STRIPS;

    const bool has_l = (c > 0);
    const bool has_r = (c < QCOLS - 1);
    const int off_l = has_l ? -1 : 0;
    const int off_r = has_r ? 4 : 3;
    const int h0 = s * ROWS;

    const size_t img = (size_t)IMG_H * IMG_W;
    const float* xb0 = x + (size_t)b * img + 4 * c;
    const float* yb0 = y + (size_t)b * img + 4 * c;

    // Pending accumulators: P1 = partial of next-to-complete output row,
    // P2 = partial of the one after.
    float4 P1mx = f4z(), P1my = f4z(), P1xx = f4z(), P1yy = f4z(), P1xy = f4z();
    float4 P2mx = f4z(), P2my = f4z(), P2xx = f4z(), P2yy = f4z(), P2xy = f4z();

    // Prologue: load input row h0-1 (clamped).
    Raw cur, nxt;
    {
        const int r0 = (h0 > 0) ? (h0 - 1) : 0;
        load_raw(xb0 + (size_t)r0 * IMG_W, yb0 + (size_t)r0 * IMG_W,
                 off_l, off_r, cur);
    }
    bool vcur = (h0 > 0);

    float local = 0.0f;
    // Main loop: j = 0..ROWS. Consumes input row h0-1+j, prefetches h0+j.
#pragma unroll 2
    for (int j = 0; j <= ROWS; ++j) {
        // --- prefetch row h0+j (clamped) ---
        const int hn = h0 + j;
        const int rn = (hn < IMG_H) ? hn : (IMG_H - 1);
        load_raw(xb0 + (size_t)rn * IMG_W, yb0 + (size_t)rn * IMG_W,
                 off_l, off_r, nxt);
        const bool vnxt = (hn < IMG_H);

        // --- compute on cur ---
        float4 fmx, fmy, fxx, fyy, fxy;
        hfilt4m(cur, vcur, has_l, has_r, fmx, fmy, fxx, fyy, fxy);

        if (j >= 2) {
            const float4 omx = f4fma(g0, fmx, P1mx);
            const float4 omy = f4fma(g0, fmy, P1my);
            const float4 oxx = f4fma(g0, fxx, P1xx);
            const float4 oyy = f4fma(g0, fyy, P1yy);
            const float4 oxy = f4fma(g0, fxy, P1xy);
            local += ssim4(omx, omy, oxx, oyy, oxy);
        }

        P1mx = f4fma(g1, fmx, P2mx); P1my = f4fma(g1, fmy, P2my);
        P1xx = f4fma(g1, fxx, P2xx); P1yy = f4fma(g1, fyy, P2yy);
        P1xy = f4fma(g1, fxy, P2xy);
        P2mx = f4s(g0, fmx); P2my = f4s(g0, fmy);
        P2xx = f4s(g0, fxx); P2yy = f4s(g0, fyy); P2xy = f4s(g0, fxy);

        cur = nxt; vcur = vnxt;
    }

    // Epilogue: consume input row h0+ROWS (already in cur), complete last row.
    {
        float4 fmx, fmy, fxx, fyy, fxy;
        hfilt4m(cur, vcur, has_l, has_r, fmx, fmy, fxx, fyy, fxy);
        const float4 omx = f4fma(g0, fmx, P1mx);
        const float4 omy = f4fma(g0, fmy, P1my);
        const float4 oxx = f4fma(g0, fxx, P1xx);
        const float4 oyy = f4fma(g0, fyy, P1yy);
        const float4 oxy = f4fma(g0, fxy, P1xy);
        local += ssim4(omx, omy, oxx, oyy, oxy);
    }

    // Block reduce.
    for (int off = 32; off > 0; off >>= 1)
        local += __shfl_down(local, off, 64);
    __shared__ float sred[NTH / 64];
    const int lane = threadIdx.x & 63;
    const int wid  = threadIdx.x >> 6;
    if (lane == 0) sred[wid] = local;
    __syncthreads();
    if (threadIdx.x == 0) {
        float t0 = 0.0f;
#pragma unroll
        for (int i = 0; i < NTH / 64; ++i) t0 += sred[i];
        partials[blockIdx.x] = t0;
    }
}

__global__ void ssim_finalize_kernel(const float* __restrict__ partials,
                                     float* __restrict__ out) {
    double acc = 0.0;
    for (int i = threadIdx.x; i < NBLK; i += FTH)
        acc += (double)partials[i];
    __shared__ double s[FTH];
    s[threadIdx.x] = acc;
    __syncthreads();
    for (int off = FTH / 2; off > 0; off >>= 1) {
        if (threadIdx.x < off) s[threadIdx.x] += s[threadIdx.x + off];
        __syncthreads();
    }
    if (threadIdx.x == 0) {
        const double mean = s[0] / (double)NPIX;
        out[0] = (float)(1.0 - mean);
    }
}

extern "C" void kernel_launch(void* const* d_in, const int* in_sizes, int n_in,
                              void* d_out, int out_size, void* d_ws, size_t ws_size,
                              hipStream_t stream) {
    const float* x = (const float*)d_in[0];
    const float* y = (const float*)d_in[1];
    float* partials = (float*)d_ws;
    float* out = (float*)d_out;

    ssim_partial_kernel<<<NBLK, NTH, 0, stream>>>(x, y, partials);
    ssim_finalize_kernel<<<1, FTH, 0, stream>>>(partials, out);
}

// Round 9
// 177.821 us; speedup vs baseline: 1.7158x; 1.0037x over previous
//
#include <hip/hip_runtime.h>

// SSIM fused, separable 3x3 Gaussian, pending-accumulator vertical filter,
// software-pipelined, short strips (ROWS=6) for high resident-wave count.

#define IMG_H 480
#define IMG_W 640
#define IMG_B 64
#define NPIX (IMG_B * IMG_H * IMG_W)   // 19,660,800
#define ROWS 6
#define STRIPS (IMG_H / ROWS)          // 80
#define QCOLS (IMG_W / 4)              // 160
#define NTH 256
#define NITEMS (IMG_B * STRIPS * QCOLS) // 819,200
#define NBLK (NITEMS / NTH)             // 3200
#define FTH 256

struct Raw { float4 x4, y4; float xa, xb, ya, yb; };

__device__ __forceinline__ float4 f4z() { return make_float4(0.f, 0.f, 0.f, 0.f); }
__device__ __forceinline__ float4 f4s(float s, float4 a) {
    return make_float4(s * a.x, s * a.y, s * a.z, s * a.w);
}
__device__ __forceinline__ float4 f4fma(float s, float4 a, float4 b) {
    return make_float4(fmaf(s, a.x, b.x), fmaf(s, a.y, b.y),
                       fmaf(s, a.z, b.z), fmaf(s, a.w, b.w));
}

__device__ __forceinline__ void load_raw(const float* __restrict__ xp,
                                         const float* __restrict__ yp,
                                         int off_l, int off_r, Raw& r) {
    r.x4 = *(const float4*)xp;
    r.y4 = *(const float4*)yp;
    r.xa = xp[off_l];
    r.xb = xp[off_r];
    r.ya = yp[off_l];
    r.yb = yp[off_r];
}

__device__ __forceinline__ void hfilt4m(const Raw& r, bool v, bool has_l, bool has_r,
                                        float4& mx, float4& my,
                                        float4& sxx, float4& syy, float4& sxy) {
    const float g0 = 0.0113f, g1 = 0.0838f;
    const float x0 = v ? r.x4.x : 0.f, x1 = v ? r.x4.y : 0.f;
    const float x2 = v ? r.x4.z : 0.f, x3 = v ? r.x4.w : 0.f;
    const float y0 = v ? r.y4.x : 0.f, y1 = v ? r.y4.y : 0.f;
    const float y2 = v ? r.y4.z : 0.f, y3 = v ? r.y4.w : 0.f;
    const float xa = (v && has_l) ? r.xa : 0.f;
    const float xb = (v && has_r) ? r.xb : 0.f;
    const float ya = (v && has_l) ? r.ya : 0.f;
    const float yb = (v && has_r) ? r.yb : 0.f;

    mx = make_float4(g0 * (xa + x1) + g1 * x0,
                     g0 * (x0 + x2) + g1 * x1,
                     g0 * (x1 + x3) + g1 * x2,
                     g0 * (x2 + xb) + g1 * x3);
    my = make_float4(g0 * (ya + y1) + g1 * y0,
                     g0 * (y0 + y2) + g1 * y1,
                     g0 * (y1 + y3) + g1 * y2,
                     g0 * (y2 + yb) + g1 * y3);

    const float qxa = xa * xa, qx0 = x0 * x0, qx1 = x1 * x1;
    const float qx2 = x2 * x2, qx3 = x3 * x3, qxb = xb * xb;
    sxx = make_float4(g0 * (qxa + qx1) + g1 * qx0,
                      g0 * (qx0 + qx2) + g1 * qx1,
                      g0 * (qx1 + qx3) + g1 * qx2,
                      g0 * (qx2 + qxb) + g1 * qx3);

    const float qya = ya * ya, qy0 = y0 * y0, qy1 = y1 * y1;
    const float qy2 = y2 * y2, qy3 = y3 * y3, qyb = yb * yb;
    syy = make_float4(g0 * (qya + qy1) + g1 * qy0,
                      g0 * (qy0 + qy2) + g1 * qy1,
                      g0 * (qy1 + qy3) + g1 * qy2,
                      g0 * (qy2 + qyb) + g1 * qy3);

    const float pa = xa * ya, p0 = x0 * y0, p1 = x1 * y1;
    const float p2 = x2 * y2, p3 = x3 * y3, pb = xb * yb;
    sxy = make_float4(g0 * (pa + p1) + g1 * p0,
                      g0 * (p0 + p2) + g1 * p1,
                      g0 * (p1 + p3) + g1 * p2,
                      g0 * (p2 + pb) + g1 * p3);
}

__device__ __forceinline__ float ssim4(float4 mx, float4 my, float4 xx,
                                       float4 yy, float4 xy) {
    const float C1 = 1e-4f, C2 = 9e-4f;
    float acc = 0.0f;
#define SSIM1(MX, MY, XX, YY, XY)                                         \
    {                                                                     \
        const float sx = (XX) - (MX) * (MX);                              \
        const float sy = (YY) - (MY) * (MY);                              \
        const float sxy_ = (XY) - (MX) * (MY);                            \
        const float num = (2.0f * (MX) * (MY) + C1) * (2.0f * sxy_ + C2); \
        const float den = ((MX) * (MX) + (MY) * (MY) + C1) *              \
                          (sx + sy + C2);                                 \
        acc += num * __builtin_amdgcn_rcpf(den);                          \
    }
    SSIM1(mx.x, my.x, xx.x, yy.x, xy.x)
    SSIM1(mx.y, my.y, xx.y, yy.y, xy.y)
    SSIM1(mx.z, my.z, xx.z, yy.z, xy.z)
    SSIM1(mx.w, my.w, xx.w, yy.w, xy.w)
#undef SSIM1
    return acc;
}

__global__ __launch_bounds__(NTH) void ssim_partial_kernel(
        const float* __restrict__ x, const float* __restrict__ y,
        float* __restrict__ partials) {
    const float g0 = 0.0113f, g1 = 0.0838f;

    const int tid = blockIdx.x * NTH + threadIdx.x;
    const int c = tid % QCOLS;
    const int t = tid / QCOLS;
    const int s = t % STRIPS;
    const int b = t / STRIPS;

    const bool has_l = (c > 0);
    const bool has_r = (c < QCOLS - 1);
    const int off_l = has_l ? -1 : 0;
    const int off_r = has_r ? 4 : 3;
    const int h0 = s * ROWS;

    const size_t img = (size_t)IMG_H * IMG_W;
    const float* xb0 = x + (size_t)b * img + 4 * c;
    const float* yb0 = y + (size_t)b * img + 4 * c;

    float4 P1mx = f4z(), P1my = f4z(), P1xx = f4z(), P1yy = f4z(), P1xy = f4z();
    float4 P2mx = f4z(), P2my = f4z(), P2xx = f4z(), P2yy = f4z(), P2xy = f4z();

    Raw cur, nxt;
    {
        const int r0 = (h0 > 0) ? (h0 - 1) : 0;
        load_raw(xb0 + (size_t)r0 * IMG_W, yb0 + (size_t)r0 * IMG_W,
                 off_l, off_r, cur);
    }
    bool vcur = (h0 > 0);

    float local = 0.0f;
#pragma unroll 2
    for (int j = 0; j <= ROWS; ++j) {
        const int hn = h0 + j;
        const int rn = (hn < IMG_H) ? hn : (IMG_H - 1);
        load_raw(xb0 + (size_t)rn * IMG_W, yb0 + (size_t)rn * IMG_W,
                 off_l, off_r, nxt);
        const bool vnxt = (hn < IMG_H);

        float4 fmx, fmy, fxx, fyy, fxy;
        hfilt4m(cur, vcur, has_l, has_r, fmx, fmy, fxx, fyy, fxy);

        if (j >= 2) {
            const float4 omx = f4fma(g0, fmx, P1mx);
            const float4 omy = f4fma(g0, fmy, P1my);
            const float4 oxx = f4fma(g0, fxx, P1xx);
            const float4 oyy = f4fma(g0, fyy, P1yy);
            const float4 oxy = f4fma(g0, fxy, P1xy);
            local += ssim4(omx, omy, oxx, oyy, oxy);
        }

        P1mx = f4fma(g1, fmx, P2mx); P1my = f4fma(g1, fmy, P2my);
        P1xx = f4fma(g1, fxx, P2xx); P1yy = f4fma(g1, fyy, P2yy);
        P1xy = f4fma(g1, fxy, P2xy);
        P2mx = f4s(g0, fmx); P2my = f4s(g0, fmy);
        P2xx = f4s(g0, fxx); P2yy = f4s(g0, fyy); P2xy = f4s(g0, fxy);

        cur = nxt; vcur = vnxt;
    }

    // Epilogue: consume final input row, complete last output row.
    {
        float4 fmx, fmy, fxx, fyy, fxy;
        hfilt4m(cur, vcur, has_l, has_r, fmx, fmy, fxx, fyy, fxy);
        const float4 omx = f4fma(g0, fmx, P1mx);
        const float4 omy = f4fma(g0, fmy, P1my);
        const float4 oxx = f4fma(g0, fxx, P1xx);
        const float4 oyy = f4fma(g0, fyy, P1yy);
        const float4 oxy = f4fma(g0, fxy, P1xy);
        local += ssim4(omx, omy, oxx, oyy, oxy);
    }

    for (int off = 32; off > 0; off >>= 1)
        local += __shfl_down(local, off, 64);
    __shared__ float sred[NTH / 64];
    const int lane = threadIdx.x & 63;
    const int wid  = threadIdx.x >> 6;
    if (lane == 0) sred[wid] = local;
    __syncthreads();
    if (threadIdx.x == 0) {
        float t0 = 0.0f;
#pragma unroll
        for (int i = 0; i < NTH / 64; ++i) t0 += sred[i];
        partials[blockIdx.x] = t0;
    }
}

__global__ void ssim_finalize_kernel(const float* __restrict__ partials,
                                     float* __restrict__ out) {
    double acc = 0.0;
    for (int i = threadIdx.x; i < NBLK; i += FTH)
        acc += (double)partials[i];
    __shared__ double s[FTH];
    s[threadIdx.x] = acc;
    __syncthreads();
    for (int off = FTH / 2; off > 0; off >>= 1) {
        if (threadIdx.x < off) s[threadIdx.x] += s[threadIdx.x + off];
        __syncthreads();
    }
    if (threadIdx.x == 0) {
        const double mean = s[0] / (double)NPIX;
        out[0] = (float)(1.0 - mean);
    }
}

extern "C" void kernel_launch(void* const* d_in, const int* in_sizes, int n_in,
                              void* d_out, int out_size, void* d_ws, size_t ws_size,
                              hipStream_t stream) {
    const float* x = (const float*)d_in[0];
    const float* y = (const float*)d_in[1];
    float* partials = (float*)d_ws;
    float* out = (float*)d_out;

    ssim_partial_kernel<<<NBLK, NTH, 0, stream>>>(x, y, partials);
    ssim_finalize_kernel<<<1, FTH, 0, stream>>>(partials, out);
}

// Round 10
// 176.407 us; speedup vs baseline: 1.7295x; 1.0080x over previous
//
#include <hip/hip_runtime.h>

// SSIM fused, separable 3x3 Gaussian, pending-accumulator vertical filter.
// Depth-2 register prefetch (fully unrolled SSA buffers), masked filtering
// only at strip prologue/epilogue rows. Thread = 4 px wide, ROWS=6 strips.

#define IMG_H 480
#define IMG_W 640
#define IMG_B 64
#define NPIX (IMG_B * IMG_H * IMG_W)   // 19,660,800
#define ROWS 6
#define STRIPS (IMG_H / ROWS)          // 80
#define QCOLS (IMG_W / 4)              // 160
#define NTH 256
#define NITEMS (IMG_B * STRIPS * QCOLS) // 819,200
#define NBLK (NITEMS / NTH)             // 3200
#define FTH 256

struct Raw { float4 x4, y4; float xa, xb, ya, yb; };

__device__ __forceinline__ float4 f4z() { return make_float4(0.f, 0.f, 0.f, 0.f); }
__device__ __forceinline__ float4 f4s(float s, float4 a) {
    return make_float4(s * a.x, s * a.y, s * a.z, s * a.w);
}
__device__ __forceinline__ float4 f4fma(float s, float4 a, float4 b) {
    return make_float4(fmaf(s, a.x, b.x), fmaf(s, a.y, b.y),
                       fmaf(s, a.z, b.z), fmaf(s, a.w, b.w));
}

__device__ __forceinline__ void load_raw(const float* __restrict__ xp,
                                         const float* __restrict__ yp,
                                         int off_l, int off_r, Raw& r) {
    r.x4 = *(const float4*)xp;
    r.y4 = *(const float4*)yp;
    r.xa = xp[off_l];
    r.xb = xp[off_r];
    r.ya = yp[off_l];
    r.yb = yp[off_r];
}

// Core horizontal filter on explicit scalars (already masked as needed).
__device__ __forceinline__ void hfilt_core(float xa, float x0, float x1, float x2,
                                           float x3, float xb,
                                           float ya, float y0, float y1, float y2,
                                           float y3, float yb,
                                           float4& mx, float4& my,
                                           float4& sxx, float4& syy, float4& sxy) {
    const float g0 = 0.0113f, g1 = 0.0838f;
    mx = make_float4(g0 * (xa + x1) + g1 * x0,
                     g0 * (x0 + x2) + g1 * x1,
                     g0 * (x1 + x3) + g1 * x2,
                     g0 * (x2 + xb) + g1 * x3);
    my = make_float4(g0 * (ya + y1) + g1 * y0,
                     g0 * (y0 + y2) + g1 * y1,
                     g0 * (y1 + y3) + g1 * y2,
                     g0 * (y2 + yb) + g1 * y3);

    const float qxa = xa * xa, qx0 = x0 * x0, qx1 = x1 * x1;
    const float qx2 = x2 * x2, qx3 = x3 * x3, qxb = xb * xb;
    sxx = make_float4(g0 * (qxa + qx1) + g1 * qx0,
                      g0 * (qx0 + qx2) + g1 * qx1,
                      g0 * (qx1 + qx3) + g1 * qx2,
                      g0 * (qx2 + qxb) + g1 * qx3);

    const float qya = ya * ya, qy0 = y0 * y0, qy1 = y1 * y1;
    const float qy2 = y2 * y2, qy3 = y3 * y3, qyb = yb * yb;
    syy = make_float4(g0 * (qya + qy1) + g1 * qy0,
                      g0 * (qy0 + qy2) + g1 * qy1,
                      g0 * (qy1 + qy3) + g1 * qy2,
                      g0 * (qy2 + qyb) + g1 * qy3);

    const float pa = xa * ya, p0 = x0 * y0, p1 = x1 * y1;
    const float p2 = x2 * y2, p3 = x3 * y3, pb = xb * yb;
    sxy = make_float4(g0 * (pa + p1) + g1 * p0,
                      g0 * (p0 + p2) + g1 * p1,
                      g0 * (p1 + p3) + g1 * p2,
                      g0 * (p2 + pb) + g1 * p3);
}

// Interior row: only column-edge masking.
__device__ __forceinline__ void hfilt4(const Raw& r, bool has_l, bool has_r,
                                       float4& mx, float4& my,
                                       float4& sxx, float4& syy, float4& sxy) {
    hfilt_core(has_l ? r.xa : 0.f, r.x4.x, r.x4.y, r.x4.z, r.x4.w,
               has_r ? r.xb : 0.f,
               has_l ? r.ya : 0.f, r.y4.x, r.y4.y, r.y4.z, r.y4.w,
               has_r ? r.yb : 0.f,
               mx, my, sxx, syy, sxy);
}

// Boundary row: full validity masking.
__device__ __forceinline__ void hfilt4m(const Raw& r, bool v, bool has_l, bool has_r,
                                        float4& mx, float4& my,
                                        float4& sxx, float4& syy, float4& sxy) {
    hfilt_core((v && has_l) ? r.xa : 0.f,
               v ? r.x4.x : 0.f, v ? r.x4.y : 0.f, v ? r.x4.z : 0.f,
               v ? r.x4.w : 0.f,
               (v && has_r) ? r.xb : 0.f,
               (v && has_l) ? r.ya : 0.f,
               v ? r.y4.x : 0.f, v ? r.y4.y : 0.f, v ? r.y4.z : 0.f,
               v ? r.y4.w : 0.f,
               (v && has_r) ? r.yb : 0.f,
               mx, my, sxx, syy, sxy);
}

__device__ __forceinline__ float ssim4(float4 mx, float4 my, float4 xx,
                                       float4 yy, float4 xy) {
    const float C1 = 1e-4f, C2 = 9e-4f;
    float acc = 0.0f;
#define SSIM1(MX, MY, XX, YY, XY)                                         \
    {                                                                     \
        const float sx = (XX) - (MX) * (MX);                              \
        const float sy = (YY) - (MY) * (MY);                              \
        const float sxy_ = (XY) - (MX) * (MY);                            \
        const float num = (2.0f * (MX) * (MY) + C1) * (2.0f * sxy_ + C2); \
        const float den = ((MX) * (MX) + (MY) * (MY) + C1) *              \
                          (sx + sy + C2);                                 \
        acc += num * __builtin_amdgcn_rcpf(den);                          \
    }
    SSIM1(mx.x, my.x, xx.x, yy.x, xy.x)
    SSIM1(mx.y, my.y, xx.y, yy.y, xy.y)
    SSIM1(mx.z, my.z, xx.z, yy.z, xy.z)
    SSIM1(mx.w, my.w, xx.w, yy.w, xy.w)
#undef SSIM1
    return acc;
}

__global__ __launch_bounds__(NTH) void ssim_partial_kernel(
        const float* __restrict__ x, const float* __restrict__ y,
        float* __restrict__ partials) {
    const float g0 = 0.0113f, g1 = 0.0838f;

    const int tid = blockIdx.x * NTH + threadIdx.x;
    const int c = tid % QCOLS;
    const int t = tid / QCOLS;
    const int s = t % STRIPS;
    const int b = t / STRIPS;

    const bool has_l = (c > 0);
    const bool has_r = (c < QCOLS - 1);
    const int off_l = has_l ? -1 : 0;
    const int off_r = has_r ? 4 : 3;
    const int h0 = s * ROWS;

    const size_t img = (size_t)IMG_H * IMG_W;
    const float* xb0 = x + (size_t)b * img + 4 * c;
    const float* yb0 = y + (size_t)b * img + 4 * c;

    float4 P1mx = f4z(), P1my = f4z(), P1xx = f4z(), P1yy = f4z(), P1xy = f4z();
    float4 P2mx = f4z(), P2my = f4z(), P2xx = f4z(), P2yy = f4z(), P2xy = f4z();

    // SSA prefetch buffers: R[j] holds input row h0-1+j. Fully unrolled
    // loop => compile-time indices => registers (<=3 live at a time).
    Raw R[ROWS + 2];

    // Prologue: issue loads for rows h0-1 and h0 (depth-2 pipeline fill).
    {
        const int r0 = (h0 > 0) ? (h0 - 1) : 0;
        load_raw(xb0 + (size_t)r0 * IMG_W, yb0 + (size_t)r0 * IMG_W,
                 off_l, off_r, R[0]);
        load_raw(xb0 + (size_t)h0 * IMG_W, yb0 + (size_t)h0 * IMG_W,
                 off_l, off_r, R[1]);
    }

    float local = 0.0f;
#pragma unroll
    for (int j = 0; j <= ROWS; ++j) {
        // Prefetch row h0+j+1 into R[j+2] (consumed at iter j+2).
        if (j < ROWS) {
            const int hn = h0 + j + 1;
            const int rn = (hn < IMG_H) ? hn : (IMG_H - 1);
            load_raw(xb0 + (size_t)rn * IMG_W, yb0 + (size_t)rn * IMG_W,
                     off_l, off_r, R[j + 2]);
        }

        // Consume row h0-1+j: j==0 may be invalid (top of image);
        // j=1..ROWS are always interior rows.
        float4 fmx, fmy, fxx, fyy, fxy;
        if (j == 0) {
            hfilt4m(R[0], h0 > 0, has_l, has_r, fmx, fmy, fxx, fyy, fxy);
        } else {
            hfilt4(R[j], has_l, has_r, fmx, fmy, fxx, fyy, fxy);
        }

        if (j >= 2) {
            const float4 omx = f4fma(g0, fmx, P1mx);
            const float4 omy = f4fma(g0, fmy, P1my);
            const float4 oxx = f4fma(g0, fxx, P1xx);
            const float4 oyy = f4fma(g0, fyy, P1yy);
            const float4 oxy = f4fma(g0, fxy, P1xy);
            local += ssim4(omx, omy, oxx, oyy, oxy);
        }

        P1mx = f4fma(g1, fmx, P2mx); P1my = f4fma(g1, fmy, P2my);
        P1xx = f4fma(g1, fxx, P2xx); P1yy = f4fma(g1, fyy, P2yy);
        P1xy = f4fma(g1, fxy, P2xy);
        P2mx = f4s(g0, fmx); P2my = f4s(g0, fmy);
        P2xx = f4s(g0, fxx); P2yy = f4s(g0, fyy); P2xy = f4s(g0, fxy);
    }

    // Epilogue: consume row h0+ROWS (in R[ROWS+1]); invalid for last strip.
    {
        float4 fmx, fmy, fxx, fyy, fxy;
        hfilt4m(R[ROWS + 1], (h0 + ROWS) < IMG_H, has_l, has_r,
                fmx, fmy, fxx, fyy, fxy);
        const float4 omx = f4fma(g0, fmx, P1mx);
        const float4 omy = f4fma(g0, fmy, P1my);
        const float4 oxx = f4fma(g0, fxx, P1xx);
        const float4 oyy = f4fma(g0, fyy, P1yy);
        const float4 oxy = f4fma(g0, fxy, P1xy);
        local += ssim4(omx, omy, oxx, oyy, oxy);
    }

    for (int off = 32; off > 0; off >>= 1)
        local += __shfl_down(local, off, 64);
    __shared__ float sred[NTH / 64];
    const int lane = threadIdx.x & 63;
    const int wid  = threadIdx.x >> 6;
    if (lane == 0) sred[wid] = local;
    __syncthreads();
    if (threadIdx.x == 0) {
        float t0 = 0.0f;
#pragma unroll
        for (int i = 0; i < NTH / 64; ++i) t0 += sred[i];
        partials[blockIdx.x] = t0;
    }
}

__global__ void ssim_finalize_kernel(const float* __restrict__ partials,
                                     float* __restrict__ out) {
    double acc = 0.0;
    for (int i = threadIdx.x; i < NBLK; i += FTH)
        acc += (double)partials[i];
    __shared__ double s[FTH];
    s[threadIdx.x] = acc;
    __syncthreads();
    for (int off = FTH / 2; off > 0; off >>= 1) {
        if (threadIdx.x < off) s[threadIdx.x] += s[threadIdx.x + off];
        __syncthreads();
    }
    if (threadIdx.x == 0) {
        const double mean = s[0] / (double)NPIX;
        out[0] = (float)(1.0 - mean);
    }
}

extern "C" void kernel_launch(void* const* d_in, const int* in_sizes, int n_in,
                              void* d_out, int out_size, void* d_ws, size_t ws_size,
                              hipStream_t stream) {
    const float* x = (const float*)d_in[0];
    const float* y = (const float*)d_in[1];
    float* partials = (float*)d_ws;
    float* out = (float*)d_out;

    ssim_partial_kernel<<<NBLK, NTH, 0, stream>>>(x, y, partials);
    ssim_finalize_kernel<<<1, FTH, 0, stream>>>(partials, out);
}